// Round 1
// baseline (260.013 us; speedup 1.0000x reference)
//
#include <hip/hip_runtime.h>
#include <math.h>

typedef float f32x4 __attribute__((ext_vector_type(4)));
typedef short s16x8 __attribute__((ext_vector_type(8)));

#define L2E 1.4426950408889634f

// accurate-enough tanh: abs err ~2e-7 (hw exp2 + hw rcp, both ~1ulp)
__device__ __forceinline__ float tanh_acc(float x) {
  float cx = fminf(fmaxf(x, -20.0f), 20.0f);
  float e = __builtin_amdgcn_exp2f(cx * 2.885390081777927f);  // 2*log2(e)
  return (e - 1.0f) * __builtin_amdgcn_rcpf(e + 1.0f);
}

// ---------------- K0: prepare W^T as bf16 hi/lo, XOR-swizzled ----------------
// Wt[e][k ^ ((e&7)<<3)] = split(W[k][e]).  RNE for both hi and lo.
__global__ void k0_prep(const float* __restrict__ W,
                        unsigned short* __restrict__ gWhi,
                        unsigned short* __restrict__ gWlo) {
  int t = blockIdx.x * 256 + threadIdx.x;  // 0..16383
  int d = t >> 7, e = t & 127;
  float w = W[d * 128 + e];
  unsigned u = __float_as_uint(w);
  unsigned hb = (u + 0x7fffu + ((u >> 16) & 1u)) >> 16;
  float whi = __uint_as_float(hb << 16);
  float lo = w - whi;  // exact
  unsigned ul = __float_as_uint(lo);
  unsigned lb = (ul + 0x7fffu + ((ul >> 16) & 1u)) >> 16;
  int addr = e * 128 + (d ^ ((e & 7) << 3));
  gWhi[addr] = (unsigned short)hb;
  gWlo[addr] = (unsigned short)lb;
}

// ---------------- K1: logits[b][j][i] = v^T tanh(W^T (x_i*x_j) + b) ----------
// block = (b, 16 i's, 16 j's); 4 waves; wave w owns i_local 4w..4w+3.
// bf16x3 MFMA: P_hi*W_hi + P_lo*W_hi + P_hi*W_lo  (err ~2^-17)
__global__ __launch_bounds__(256, 2) void k1_logits(
    const float* __restrict__ x, const unsigned short* __restrict__ gWhi,
    const unsigned short* __restrict__ gWlo, const float* __restrict__ apb,
    const float* __restrict__ av, float* __restrict__ Lg) {
  __shared__ __align__(16) unsigned short sWhi[16384];
  __shared__ __align__(16) unsigned short sWlo[16384];
  __shared__ __align__(16) float sXj[16 * 132];  // pad 132: 2-way max on reads

  const int tid = threadIdx.x;
  const int b = blockIdx.z, i0 = blockIdx.y * 16, j0 = blockIdx.x * 16;

  {  // stage W hi/lo (pure copy, pre-swizzled) + x_j rows
    const uint4* shi = (const uint4*)gWhi;
    const uint4* slo = (const uint4*)gWlo;
    uint4* dhi = (uint4*)sWhi;
    uint4* dlo = (uint4*)sWlo;
#pragma unroll
    for (int r = 0; r < 8; ++r) {
      dhi[tid + 256 * r] = shi[tid + 256 * r];
      dlo[tid + 256 * r] = slo[tid + 256 * r];
    }
    const float4* xsrc = (const float4*)(x + ((size_t)(b * 256 + j0)) * 128);
#pragma unroll
    for (int r = 0; r < 2; ++r) {
      int v = tid + 256 * r;  // 0..511
      int jl = v >> 5, k4 = v & 31;
      *(float4*)&sXj[jl * 132 + k4 * 4] = xsrc[v];
    }
  }
  __syncthreads();

  const int lane = tid & 63;
  const int w = tid >> 6;
  const int quad = lane >> 4;
  const int col = lane & 15;
  const int swz = (col & 7) << 3;

  f32x4 acc[4][8];
#pragma unroll
  for (int mt = 0; mt < 4; ++mt)
#pragma unroll
    for (int et = 0; et < 8; ++et) acc[mt][et] = (f32x4){0.f, 0.f, 0.f, 0.f};

  const float* xib = x + ((size_t)(b * 256 + i0 + 4 * w)) * 128;

#pragma unroll
  for (int kstep = 0; kstep < 4; ++kstep) {
    const int k0 = kstep * 32 + quad * 8;
    // A-frag: m=lane&15 -> pair row = j_local; k = quad*8+q (+32*kstep)
    float4 xj0 = *(const float4*)&sXj[col * 132 + k0];
    float4 xj1 = *(const float4*)&sXj[col * 132 + k0 + 4];
    s16x8 Ah[4], Al[4];
#pragma unroll
    for (int mt = 0; mt < 4; ++mt) {
      const float* xip = xib + mt * 128 + k0;
      float4 xi0 = *(const float4*)xip;
      float4 xi1 = *(const float4*)(xip + 4);
      float pv[8];
      pv[0] = xi0.x * xj0.x; pv[1] = xi0.y * xj0.y;
      pv[2] = xi0.z * xj0.z; pv[3] = xi0.w * xj0.w;
      pv[4] = xi1.x * xj1.x; pv[5] = xi1.y * xj1.y;
      pv[6] = xi1.z * xj1.z; pv[7] = xi1.w * xj1.w;
#pragma unroll
      for (int q = 0; q < 8; ++q) {
        unsigned u = __float_as_uint(pv[q]);
        unsigned uh = u & 0xffff0000u;          // hi = trunc
        float r = pv[q] - __uint_as_float(uh);  // exact residual
        unsigned ul = __float_as_uint(r);
        Ah[mt][q] = (short)(u >> 16);
        Al[mt][q] = (short)((ul + 0x8000u) >> 16);  // lo = round-half-up
      }
    }
#pragma unroll
    for (int et = 0; et < 8; ++et) {
      const int e = col + 16 * et;
      const int addr = e * 128 + (k0 ^ swz);
      s16x8 bh = *(const s16x8*)&sWhi[addr];
      s16x8 bl = *(const s16x8*)&sWlo[addr];
#pragma unroll
      for (int mt = 0; mt < 4; ++mt) {
        acc[mt][et] = __builtin_amdgcn_mfma_f32_16x16x32_bf16(Ah[mt], bh, acc[mt][et], 0, 0, 0);
        acc[mt][et] = __builtin_amdgcn_mfma_f32_16x16x32_bf16(Al[mt], bh, acc[mt][et], 0, 0, 0);
        acc[mt][et] = __builtin_amdgcn_mfma_f32_16x16x32_bf16(Ah[mt], bl, acc[mt][et], 0, 0, 0);
      }
    }
  }

  float bias[8], vw[8];
#pragma unroll
  for (int et = 0; et < 8; ++et) {
    bias[et] = apb[col + 16 * et];
    vw[et] = av[col + 16 * et];
  }

  // epilogue: tanh, weight by v, reduce over e (cols = 16 lanes/group)
#pragma unroll
  for (int mt = 0; mt < 4; ++mt) {
    float ls0 = 0.f, ls1 = 0.f, ls2 = 0.f, ls3 = 0.f;
#pragma unroll
    for (int et = 0; et < 8; ++et) {
      ls0 += tanh_acc(acc[mt][et][0] + bias[et]) * vw[et];
      ls1 += tanh_acc(acc[mt][et][1] + bias[et]) * vw[et];
      ls2 += tanh_acc(acc[mt][et][2] + bias[et]) * vw[et];
      ls3 += tanh_acc(acc[mt][et][3] + bias[et]) * vw[et];
    }
#pragma unroll
    for (int mask = 1; mask < 16; mask <<= 1) {
      ls0 += __shfl_xor(ls0, mask);
      ls1 += __shfl_xor(ls1, mask);
      ls2 += __shfl_xor(ls2, mask);
      ls3 += __shfl_xor(ls3, mask);
    }
    if (col < 4) {
      float outv = (col == 0) ? ls0 : (col == 1) ? ls1 : (col == 2) ? ls2 : ls3;
      const int jl = quad * 4 + col;  // C/D row = quad*4 + reg
      Lg[((size_t)(b * 256 + j0 + jl)) * 256 + i0 + 4 * w + mt] = outv;
    }
  }
}

// ---------------- K2: softmax over i (rows of Lg[b][j][i]), in place --------
__global__ void k2_softmax(float* __restrict__ Lg) {
  const int w = threadIdx.x >> 6, lane = threadIdx.x & 63;
  const int row = blockIdx.x * 4 + w;  // 0..4095 = b*256+j
  float4* p = (float4*)(Lg + (size_t)row * 256);
  float4 v = p[lane];
  float m = fmaxf(fmaxf(v.x, v.y), fmaxf(v.z, v.w));
#pragma unroll
  for (int mask = 1; mask < 64; mask <<= 1) m = fmaxf(m, __shfl_xor(m, mask));
  v.x = __builtin_amdgcn_exp2f((v.x - m) * L2E);
  v.y = __builtin_amdgcn_exp2f((v.y - m) * L2E);
  v.z = __builtin_amdgcn_exp2f((v.z - m) * L2E);
  v.w = __builtin_amdgcn_exp2f((v.w - m) * L2E);
  float s = v.x + v.y + v.z + v.w;
#pragma unroll
  for (int mask = 1; mask < 64; mask <<= 1) s += __shfl_xor(s, mask);
  float inv = 1.0f / s;
  v.x *= inv; v.y *= inv; v.z *= inv; v.w *= inv;
  p[lane] = v;
}

// ---------------- K3: agg[b][i][d] = sum_j att[b][j][i] * x[b][j][d] --------
__global__ void k3_agg(const float* __restrict__ Lg, const float* __restrict__ x,
                       float* __restrict__ agg) {
  const int b = blockIdx.y, i0 = blockIdx.x * 16;
  const int tid = threadIdx.x;
  const int il = tid >> 4, d0 = (tid & 15) * 8;
  __shared__ float satt[16][17];
  __shared__ float sx[16 * 128];
  float acc[8] = {0.f, 0.f, 0.f, 0.f, 0.f, 0.f, 0.f, 0.f};
  for (int jj = 0; jj < 256; jj += 16) {
    __syncthreads();
    satt[tid >> 4][tid & 15] =
        Lg[((size_t)(b * 256 + jj + (tid >> 4))) * 256 + i0 + (tid & 15)];
    const float4* xsrc = (const float4*)(x + ((size_t)(b * 256 + jj)) * 128);
    ((float4*)sx)[tid] = xsrc[tid];
    ((float4*)sx)[tid + 256] = xsrc[tid + 256];
    __syncthreads();
#pragma unroll
    for (int jl = 0; jl < 16; ++jl) {
      float a = satt[jl][il];
      const float* xr = &sx[jl * 128 + d0];
#pragma unroll
      for (int q = 0; q < 8; ++q) acc[q] += a * xr[q];
    }
  }
  float* dst = agg + ((size_t)(b * 256 + i0 + il)) * 128 + d0;
#pragma unroll
  for (int q = 0; q < 8; ++q) dst[q] = acc[q];
}

// ---------------- K4: h = selu(BN(agg@pwa + x@pwoa + biases)), fp64 acc -----
__global__ void k4_h(const float* __restrict__ agg, const float* __restrict__ x,
                     const float* __restrict__ pwa, const float* __restrict__ pwoa,
                     const float* __restrict__ pwab, const float* __restrict__ pwob,
                     const float* __restrict__ gam, const float* __restrict__ bet,
                     const float* __restrict__ mea, const float* __restrict__ varr,
                     float* __restrict__ h) {
  const int b = blockIdx.y, i0 = blockIdx.x * 16;
  const int tid = threadIdx.x;
  const int il = tid >> 4, d0 = (tid & 15) * 8;
  __shared__ float sa[2048], sx[2048];
  const float4* as = (const float4*)(agg + ((size_t)(b * 256 + i0)) * 128);
  const float4* xs = (const float4*)(x + ((size_t)(b * 256 + i0)) * 128);
  ((float4*)sa)[tid] = as[tid];
  ((float4*)sa)[tid + 256] = as[tid + 256];
  ((float4*)sx)[tid] = xs[tid];
  ((float4*)sx)[tid + 256] = xs[tid + 256];
  __syncthreads();
  double acc[8] = {0, 0, 0, 0, 0, 0, 0, 0};
  for (int k = 0; k < 128; ++k) {
    double a = (double)sa[il * 128 + k];
    const float* wr = pwa + k * 128 + d0;
#pragma unroll
    for (int q = 0; q < 8; ++q) acc[q] += a * (double)wr[q];
  }
  for (int k = 0; k < 128; ++k) {
    double a = (double)sx[il * 128 + k];
    const float* wr = pwoa + k * 128 + d0;
#pragma unroll
    for (int q = 0; q < 8; ++q) acc[q] += a * (double)wr[q];
  }
  float* dst = h + ((size_t)(b * 256 + i0 + il)) * 128 + d0;
#pragma unroll
  for (int q = 0; q < 8; ++q) {
    int d = d0 + q;
    double hv = acc[q] + (double)pwab[d] + (double)pwob[d];
    double bn = (hv - (double)mea[d]) * (1.0 / sqrt((double)varr[d] + 1e-5)) *
                    (double)gam[d] +
                (double)bet[d];
    float bf = (float)bn;
    float se = bf > 0.f ? 1.0507009873554805f * bf
                        : 1.7580993408473766f *  // scale*alpha
                              (__builtin_amdgcn_exp2f(bf * L2E) - 1.0f);
    dst[q] = se;
  }
}

// ---------------- K5: scores, stable top-128, gather h*score ----------------
__global__ void k5_topk(const float* __restrict__ h, const float* __restrict__ plw,
                        const float* __restrict__ plb, float* __restrict__ out) {
  const int b = blockIdx.x, t = threadIdx.x;
  __shared__ float sc[256];
  __shared__ int sel[128];
  const float* hr = h + ((size_t)(b * 256 + t)) * 128;
  double z = 0.0;
  for (int k = 0; k < 128; ++k) z += (double)hr[k] * (double)plw[k];
  z += (double)plb[0];
  sc[t] = (float)(1.0 / (1.0 + exp(-z)));
  __syncthreads();
  const float st = sc[t];
  int rank = 0;
  for (int m = 0; m < 256; ++m) {
    float sm = sc[m];
    rank += (sm > st) || (sm == st && m < t);  // stable descending
  }
  if (rank < 128) sel[rank] = t;
  __syncthreads();
  const float4* h4 = (const float4*)(h + (size_t)b * 256 * 128);
  float4* o4 = (float4*)(out + (size_t)b * 128 * 128);
#pragma unroll
  for (int r = 0; r < 16; ++r) {
    int v = t + 256 * r;  // 0..4095
    int row = v >> 5, q = v & 31;
    int src = sel[row];
    float ss = sc[src];
    float4 hv = h4[src * 32 + q];
    float4 ov;
    ov.x = hv.x * ss; ov.y = hv.y * ss; ov.z = hv.z * ss; ov.w = hv.w * ss;
    o4[row * 32 + q] = ov;
  }
}

extern "C" void kernel_launch(void* const* d_in, const int* in_sizes, int n_in,
                              void* d_out, int out_size, void* d_ws, size_t ws_size,
                              hipStream_t stream) {
  const float* x    = (const float*)d_in[0];
  const float* apw  = (const float*)d_in[1];
  const float* apb  = (const float*)d_in[2];
  const float* av   = (const float*)d_in[3];
  const float* pwa  = (const float*)d_in[4];
  const float* pwab = (const float*)d_in[5];
  const float* pwoa = (const float*)d_in[6];
  const float* pwob = (const float*)d_in[7];
  const float* gam  = (const float*)d_in[8];
  const float* bet  = (const float*)d_in[9];
  const float* mea  = (const float*)d_in[10];
  const float* varr = (const float*)d_in[11];
  const float* plw  = (const float*)d_in[12];
  const float* plb  = (const float*)d_in[13];
  float* out = (float*)d_out;

  // workspace layout (8.45 MB): Wt hi/lo | logits/att | agg | h
  unsigned short* gWhi = (unsigned short*)d_ws;
  unsigned short* gWlo = gWhi + 16384;
  float* Lg  = (float*)((char*)d_ws + 65536);
  float* agg = Lg + (size_t)16 * 256 * 256;
  float* hb  = agg + (size_t)16 * 256 * 128;

  k0_prep<<<64, 256, 0, stream>>>(apw, gWhi, gWlo);
  k1_logits<<<dim3(16, 16, 16), 256, 0, stream>>>(x, gWhi, gWlo, apb, av, Lg);
  k2_softmax<<<1024, 256, 0, stream>>>(Lg);
  k3_agg<<<dim3(16, 16), 256, 0, stream>>>(Lg, x, agg);
  k4_h<<<dim3(16, 16), 256, 0, stream>>>(agg, x, pwa, pwoa, pwab, pwob, gam, bet,
                                         mea, varr, hb);
  k5_topk<<<16, 256, 0, stream>>>(hb, plw, plb, out);
}